// Round 1
// baseline (401.429 us; speedup 1.0000x reference)
//
#include <hip/hip_runtime.h>
#include <math.h>

#define ROWS 32

// ---------------- GEMM: xl = x @ Wl, xr = x @ Wr ----------------
__global__ __launch_bounds__(256) void gemm_xlxr(
    const float* __restrict__ x, const float* __restrict__ Wl,
    const float* __restrict__ Wr, float* __restrict__ xl,
    float* __restrict__ xr, int n) {
  __shared__ float xs[256][36];  // transposed tile xs[k][r], stride 36 floats = 144B (16B aligned)
  const int tid = threadIdx.x;
  const int row0 = blockIdx.x * ROWS;
  const float4* xg = reinterpret_cast<const float4*>(x);
#pragma unroll
  for (int i = 0; i < 8; ++i) {
    int f = tid + i * 256;       // 0..2047 float4 slots in tile
    int row = f >> 6;            // 64 float4 per row
    int k4 = f & 63;
    float4 v = make_float4(0.f, 0.f, 0.f, 0.f);
    if (row0 + row < n) v = xg[(size_t)(row0 + row) * 64 + k4];
    xs[k4 * 4 + 0][row] = v.x;
    xs[k4 * 4 + 1][row] = v.y;
    xs[k4 * 4 + 2][row] = v.z;
    xs[k4 * 4 + 3][row] = v.w;
  }
  __syncthreads();
  const int c = tid & 127;
  const int sel = tid >> 7;
  const float* __restrict__ W = sel ? Wr : Wl;
  float acc[ROWS];
#pragma unroll
  for (int r = 0; r < ROWS; ++r) acc[r] = 0.f;
#pragma unroll 4
  for (int k = 0; k < 256; ++k) {
    float w = W[k * 128 + c];
    const float4* xk = reinterpret_cast<const float4*>(&xs[k][0]);
#pragma unroll
    for (int j = 0; j < 8; ++j) {
      float4 v = xk[j];
      acc[j * 4 + 0] = fmaf(v.x, w, acc[j * 4 + 0]);
      acc[j * 4 + 1] = fmaf(v.y, w, acc[j * 4 + 1]);
      acc[j * 4 + 2] = fmaf(v.z, w, acc[j * 4 + 2]);
      acc[j * 4 + 3] = fmaf(v.w, w, acc[j * 4 + 3]);
    }
  }
  float* __restrict__ o = sel ? xr : xl;
#pragma unroll
  for (int r = 0; r < ROWS; ++r) {
    if (row0 + r < n) o[(size_t)(row0 + r) * 128 + c] = acc[r];
  }
}

// ---------------- CSR build ----------------
__global__ void count_deg(const int* __restrict__ ei, int* __restrict__ deg, int E) {
  int e = blockIdx.x * 256 + threadIdx.x;
  if (e < E) atomicAdd(&deg[ei[E + e]], 1);
}

__global__ void scan1(const int* __restrict__ deg, int* __restrict__ offs,
                      int* __restrict__ bsum, int n) {
  __shared__ int tmp[256];
  int t = threadIdx.x;
  int g = blockIdx.x * 256 + t;
  int v = (g < n) ? deg[g] : 0;
  tmp[t] = v;
  int x = v;
  for (int off = 1; off < 256; off <<= 1) {
    __syncthreads();
    int y = (t >= off) ? tmp[t - off] : 0;
    __syncthreads();
    x += y;
    tmp[t] = x;
  }
  if (g < n) offs[g] = x - v;  // exclusive within block
  if (t == 255) bsum[blockIdx.x] = x;
}

__global__ void scan2(int* __restrict__ bsum, int nb) {
  __shared__ int tmp[256];
  int t = threadIdx.x;
  int v = (t < nb) ? bsum[t] : 0;
  tmp[t] = v;
  int x = v;
  for (int off = 1; off < 256; off <<= 1) {
    __syncthreads();
    int y = (t >= off) ? tmp[t - off] : 0;
    __syncthreads();
    x += y;
    tmp[t] = x;
  }
  if (t < nb) bsum[t] = x - v;  // exclusive
}

__global__ void scan3(int* __restrict__ offs, const int* __restrict__ bsum,
                      int* __restrict__ cursor, int n, int E) {
  int g = blockIdx.x * 256 + threadIdx.x;
  if (g < n) {
    int v = offs[g] + bsum[blockIdx.x];
    offs[g] = v;
    cursor[g] = v;
  }
  if (g == 0) offs[n] = E;
}

__global__ void fill_csr(const int* __restrict__ ei, int* __restrict__ cursor,
                         int* __restrict__ csr, int E) {
  int e = blockIdx.x * 256 + threadIdx.x;
  if (e < E) {
    int d = ei[E + e];
    int pos = atomicAdd(&cursor[d], 1);
    csr[pos] = ei[e];
  }
}

// ---------------- main GAT kernel: online segment softmax + accumulate ----------------
__device__ __forceinline__ float red32(float v) {
  v += __shfl_xor(v, 16);
  v += __shfl_xor(v, 8);
  v += __shfl_xor(v, 4);
  v += __shfl_xor(v, 2);
  v += __shfl_xor(v, 1);
  return v;
}

__global__ __launch_bounds__(256) void gat_main(
    const float* __restrict__ xl, const float* __restrict__ xr,
    const int* __restrict__ csr, const int* __restrict__ offs,
    const float* __restrict__ att, const float* __restrict__ bias,
    float* __restrict__ out, int n) {
  const int tid = threadIdx.x;
  const int sub = tid >> 7;  // 2 nodes per block
  const int c = tid & 127;   // channel = head*32 + ch
  const int i = blockIdx.x * 2 + sub;
  if (i >= n) return;

  const float att_c = att[c];
  const float b_c = bias[c];
  const float xr_i = xr[(size_t)i * 128 + c];

  // self loop (always present) initializes online softmax state
  float xl_v = xl[(size_t)i * 128 + c];
  float z = xl_v + xr_i;
  float t = fmaxf(z, 0.2f * z);  // leaky_relu, slope 0.2 < 1
  float m = red32(att_c * t);    // per-head logit, broadcast in 32-lane group
  float s = 1.0f;
  float acc = xl_v;

  const int e0 = offs[i], e1 = offs[i + 1];
  for (int e = e0; e < e1; ++e) {
    int src = csr[e];
    float v = xl[(size_t)src * 128 + c];
    float zz = v + xr_i;
    float tt = fmaxf(zz, 0.2f * zz);
    float l = red32(att_c * tt);
    float mn = fmaxf(m, l);
    float sc = __expf(m - mn);
    float p = __expf(l - mn);
    acc = acc * sc + p * v;
    s = s * sc + p;
    m = mn;
  }
  out[(size_t)i * 128 + c] = fmaxf(acc / (s + 1e-16f) + b_c, 0.0f);
}

// ---------------- launcher ----------------
extern "C" void kernel_launch(void* const* d_in, const int* in_sizes, int n_in,
                              void* d_out, int out_size, void* d_ws, size_t ws_size,
                              hipStream_t stream) {
  const float* x   = (const float*)d_in[0];
  const int*   ei  = (const int*)d_in[1];
  const float* Wl  = (const float*)d_in[2];
  const float* Wr  = (const float*)d_in[3];
  const float* att = (const float*)d_in[4];
  const float* bias= (const float*)d_in[5];
  float* out = (float*)d_out;
  const int n = in_sizes[0] / 256;
  const int E = in_sizes[1] / 2;

  float* xl = (float*)d_ws;
  float* xr = xl + (size_t)n * 128;
  int* deg  = (int*)(xr + (size_t)n * 128);
  int* offs = deg + n;
  int* bsum = offs + n + 1;
  int* csr  = bsum + 256;
  int* cursor = csr + E;

  hipMemsetAsync(deg, 0, n * sizeof(int), stream);
  gemm_xlxr<<<(n + ROWS - 1) / ROWS, 256, 0, stream>>>(x, Wl, Wr, xl, xr, n);
  count_deg<<<(E + 255) / 256, 256, 0, stream>>>(ei, deg, E);
  const int nb = (n + 255) / 256;
  scan1<<<nb, 256, 0, stream>>>(deg, offs, bsum, n);
  scan2<<<1, 256, 0, stream>>>(bsum, nb);
  scan3<<<nb, 256, 0, stream>>>(offs, bsum, cursor, n, E);
  fill_csr<<<(E + 255) / 256, 256, 0, stream>>>(ei, cursor, csr, E);
  gat_main<<<(n + 1) / 2, 256, 0, stream>>>(xl, xr, csr, offs, att, bias, out, n);
}

// Round 2
// 292.406 us; speedup vs baseline: 1.3728x; 1.3728x over previous
//
#include <hip/hip_runtime.h>
#include <math.h>

// ---------------- GEMM v2: register-tiled, xl = x @ Wl, xr = x @ Wr ----------------
#define GM_ROWS 64
#define GM_KC 64

__global__ __launch_bounds__(256) void gemm_v2(
    const float* __restrict__ x, const float* __restrict__ Wl,
    const float* __restrict__ Wr, float* __restrict__ xl,
    float* __restrict__ xr, int n) {
  __shared__ float xsT[GM_KC][GM_ROWS + 8];  // [k_local][row], pad 8 (16B-aligned rows)
  __shared__ float ws[GM_KC][128];
  const int tid = threadIdx.x;
  const int row0 = blockIdx.x * GM_ROWS;
  const int sel = blockIdx.y;
  const float* __restrict__ W = sel ? Wr : Wl;
  float* __restrict__ o = sel ? xr : xl;
  const int tr = tid >> 5;  // 0..7: row sub-block of 8
  const int tc = tid & 31;  // col group of 4

  float acc[8][4];
#pragma unroll
  for (int i = 0; i < 8; ++i)
#pragma unroll
    for (int j = 0; j < 4; ++j) acc[i][j] = 0.f;

  const float4* xg = reinterpret_cast<const float4*>(x);
  const float4* wg = reinterpret_cast<const float4*>(W);

  for (int k0 = 0; k0 < 256; k0 += GM_KC) {
    // stage x tile (64 rows x 64 k), transposed: 1024 float4, 4 per thread
#pragma unroll
    for (int i = 0; i < 4; ++i) {
      int f = tid + i * 256;
      int row = f >> 4;  // 16 float4 per row-chunk
      int k4 = f & 15;
      float4 v = make_float4(0.f, 0.f, 0.f, 0.f);
      if (row0 + row < n) v = xg[(size_t)(row0 + row) * 64 + (k0 >> 2) + k4];
      xsT[k4 * 4 + 0][row] = v.x;
      xsT[k4 * 4 + 1][row] = v.y;
      xsT[k4 * 4 + 2][row] = v.z;
      xsT[k4 * 4 + 3][row] = v.w;
    }
    // stage W tile (64 k x 128 c): 2048 float4, 8 per thread
#pragma unroll
    for (int i = 0; i < 8; ++i) {
      int f = tid + i * 256;
      int kk = f >> 5;  // 32 float4 per k-row
      int c4 = f & 31;
      float4 v = wg[(size_t)(k0 + kk) * 32 + c4];
      *reinterpret_cast<float4*>(&ws[kk][c4 * 4]) = v;
    }
    __syncthreads();
#pragma unroll 8
    for (int kk = 0; kk < GM_KC; ++kk) {
      float4 w4 = *reinterpret_cast<const float4*>(&ws[kk][tc * 4]);
      float4 xa = *reinterpret_cast<const float4*>(&xsT[kk][tr * 8]);
      float4 xb = *reinterpret_cast<const float4*>(&xsT[kk][tr * 8 + 4]);
      float xv[8] = {xa.x, xa.y, xa.z, xa.w, xb.x, xb.y, xb.z, xb.w};
#pragma unroll
      for (int i = 0; i < 8; ++i) {
        acc[i][0] = fmaf(xv[i], w4.x, acc[i][0]);
        acc[i][1] = fmaf(xv[i], w4.y, acc[i][1]);
        acc[i][2] = fmaf(xv[i], w4.z, acc[i][2]);
        acc[i][3] = fmaf(xv[i], w4.w, acc[i][3]);
      }
    }
    __syncthreads();
  }
#pragma unroll
  for (int i = 0; i < 8; ++i) {
    int row = row0 + tr * 8 + i;
    if (row < n) {
      float4 v = make_float4(acc[i][0], acc[i][1], acc[i][2], acc[i][3]);
      reinterpret_cast<float4*>(&o[(size_t)row * 128])[tc] = v;
    }
  }
}

// ---------------- CSR build ----------------
__global__ void count_deg(const int* __restrict__ ei, int* __restrict__ deg, int E) {
  int e = blockIdx.x * 256 + threadIdx.x;
  if (e < E) atomicAdd(&deg[ei[E + e]], 1);
}

__global__ void scan1(const int* __restrict__ deg, int* __restrict__ offs,
                      int* __restrict__ bsum, int n) {
  __shared__ int tmp[256];
  int t = threadIdx.x;
  int g = blockIdx.x * 256 + t;
  int v = (g < n) ? deg[g] : 0;
  tmp[t] = v;
  int x = v;
  for (int off = 1; off < 256; off <<= 1) {
    __syncthreads();
    int y = (t >= off) ? tmp[t - off] : 0;
    __syncthreads();
    x += y;
    tmp[t] = x;
  }
  if (g < n) offs[g] = x - v;
  if (t == 255) bsum[blockIdx.x] = x;
}

__global__ void scan2(int* __restrict__ bsum, int nb) {
  __shared__ int tmp[256];
  int t = threadIdx.x;
  int v = (t < nb) ? bsum[t] : 0;
  tmp[t] = v;
  int x = v;
  for (int off = 1; off < 256; off <<= 1) {
    __syncthreads();
    int y = (t >= off) ? tmp[t - off] : 0;
    __syncthreads();
    x += y;
    tmp[t] = x;
  }
  if (t < nb) bsum[t] = x - v;
}

__global__ void scan3(int* __restrict__ offs, const int* __restrict__ bsum,
                      int* __restrict__ cursor, int n, int E) {
  int g = blockIdx.x * 256 + threadIdx.x;
  if (g < n) {
    int v = offs[g] + bsum[blockIdx.x];
    offs[g] = v;
    cursor[g] = v;
  }
  if (g == 0) offs[n] = E;
}

__global__ void fill_csr(const int* __restrict__ ei, int* __restrict__ cursor,
                         int* __restrict__ csr, int E) {
  int e = blockIdx.x * 256 + threadIdx.x;
  if (e < E) {
    int d = ei[E + e];
    int pos = atomicAdd(&cursor[d], 1);
    csr[pos] = ei[e];
  }
}

// ---------------- main GAT kernel ----------------
__device__ __forceinline__ float red32(float v) {
  v += __shfl_xor(v, 16);
  v += __shfl_xor(v, 8);
  v += __shfl_xor(v, 4);
  v += __shfl_xor(v, 2);
  v += __shfl_xor(v, 1);
  return v;
}

__global__ __launch_bounds__(256) void gat_main(
    const float* __restrict__ xl, const float* __restrict__ xr,
    const int* __restrict__ csr, const int* __restrict__ offs,
    const float* __restrict__ att, const float* __restrict__ bias,
    float* __restrict__ out, int n) {
  const int tid = threadIdx.x;
  const int sub = tid >> 7;  // 2 nodes per block
  const int c = tid & 127;   // channel = head*32 + ch
  const int lane = tid & 63;
  const int i = blockIdx.x * 2 + sub;
  if (i >= n) return;

  const float att_c = att[c];
  const float b_c = bias[c];
  const float xr_i = xr[(size_t)i * 128 + c];

  // self loop initializes online-softmax state
  float xl_v = xl[(size_t)i * 128 + c];
  float z = xl_v + xr_i;
  float t = fmaxf(z, 0.2f * z);
  float m = red32(att_c * t);
  float s = 1.0f;
  float acc = xl_v;

  const int e0 = offs[i], e1 = offs[i + 1];
  int e = e0;
  const int nbatch = (e1 - e0) >> 2;

  float nv0, nv1, nv2, nv3;
  if (nbatch > 0) {
    int s0 = csr[e], s1 = csr[e + 1], s2 = csr[e + 2], s3 = csr[e + 3];
    nv0 = xl[(size_t)s0 * 128 + c];
    nv1 = xl[(size_t)s1 * 128 + c];
    nv2 = xl[(size_t)s2 * 128 + c];
    nv3 = xl[(size_t)s3 * 128 + c];
  }
  for (int b = 0; b < nbatch; ++b) {
    float v0 = nv0, v1 = nv1, v2 = nv2, v3 = nv3;
    e += 4;
    if (b + 1 < nbatch) {  // prefetch next batch
      int s0 = csr[e], s1 = csr[e + 1], s2 = csr[e + 2], s3 = csr[e + 3];
      nv0 = xl[(size_t)s0 * 128 + c];
      nv1 = xl[(size_t)s1 * 128 + c];
      nv2 = xl[(size_t)s2 * 128 + c];
      nv3 = xl[(size_t)s3 * 128 + c];
    }
    // a_e = att_c * leaky(v_e + xr_i)
    float z0 = v0 + xr_i, z1 = v1 + xr_i, z2 = v2 + xr_i, z3 = v3 + xr_i;
    float a0 = att_c * fmaxf(z0, 0.2f * z0);
    float a1 = att_c * fmaxf(z1, 0.2f * z1);
    float a2 = att_c * fmaxf(z2, 0.2f * z2);
    float a3 = att_c * fmaxf(z3, 0.2f * z3);
    // merged butterfly: 4 sums over 32-lane groups
    a0 += __shfl_xor(a0, 16);
    a1 += __shfl_xor(a1, 16);
    a2 += __shfl_xor(a2, 16);
    a3 += __shfl_xor(a3, 16);
    float bb0 = (lane & 16) ? a1 : a0;
    float bb1 = (lane & 16) ? a3 : a2;
    bb0 += __shfl_xor(bb0, 8);
    bb1 += __shfl_xor(bb1, 8);
    float cc = (lane & 8) ? bb1 : bb0;
    cc += __shfl_xor(cc, 4);
    cc += __shfl_xor(cc, 2);
    cc += __shfl_xor(cc, 1);
    // cc: (bit16,bit8) = (0,0)->l0, (1,0)->l1, (0,1)->l2, (1,1)->l3
    float d = fmaxf(cc, __shfl_xor(cc, 16));
    d = fmaxf(d, __shfl_xor(d, 8));  // max(l0..l3) everywhere
    float mn = fmaxf(m, d);
    float sc = __expf(m - mn);
    float pc = __expf(cc - mn);  // p for this lane's subgroup edge
    int base = lane & 32;
    float p0 = __shfl(pc, base + 0);
    float p1 = __shfl(pc, base + 16);
    float p2 = __shfl(pc, base + 8);
    float p3 = __shfl(pc, base + 24);
    acc = acc * sc + p0 * v0 + p1 * v1 + p2 * v2 + p3 * v3;
    s = s * sc + (p0 + p1 + p2 + p3);
    m = mn;
  }
  // tail (0..3 edges)
  for (; e < e1; ++e) {
    int src = csr[e];
    float v = xl[(size_t)src * 128 + c];
    float zz = v + xr_i;
    float tt = fmaxf(zz, 0.2f * zz);
    float l = red32(att_c * tt);
    float mn = fmaxf(m, l);
    float sc = __expf(m - mn);
    float p = __expf(l - mn);
    acc = acc * sc + p * v;
    s = s * sc + p;
    m = mn;
  }
  out[(size_t)i * 128 + c] = fmaxf(acc / (s + 1e-16f) + b_c, 0.0f);
}

// ---------------- launcher ----------------
extern "C" void kernel_launch(void* const* d_in, const int* in_sizes, int n_in,
                              void* d_out, int out_size, void* d_ws, size_t ws_size,
                              hipStream_t stream) {
  const float* x    = (const float*)d_in[0];
  const int*   ei   = (const int*)d_in[1];
  const float* Wl   = (const float*)d_in[2];
  const float* Wr   = (const float*)d_in[3];
  const float* att  = (const float*)d_in[4];
  const float* bias = (const float*)d_in[5];
  float* out = (float*)d_out;
  const int n = in_sizes[0] / 256;
  const int E = in_sizes[1] / 2;

  float* xl = (float*)d_ws;
  float* xr = xl + (size_t)n * 128;
  int* deg    = (int*)(xr + (size_t)n * 128);
  int* offs   = deg + n;
  int* bsum   = offs + n + 1;
  int* csr    = bsum + 256;
  int* cursor = csr + E;

  hipMemsetAsync(deg, 0, n * sizeof(int), stream);
  dim3 ggrid((n + GM_ROWS - 1) / GM_ROWS, 2);
  gemm_v2<<<ggrid, 256, 0, stream>>>(x, Wl, Wr, xl, xr, n);
  count_deg<<<(E + 255) / 256, 256, 0, stream>>>(ei, deg, E);
  const int nb = (n + 255) / 256;
  scan1<<<nb, 256, 0, stream>>>(deg, offs, bsum, n);
  scan2<<<1, 256, 0, stream>>>(bsum, nb);
  scan3<<<nb, 256, 0, stream>>>(offs, bsum, cursor, n, E);
  fill_csr<<<(E + 255) / 256, 256, 0, stream>>>(ei, cursor, csr, E);
  gat_main<<<(n + 1) / 2, 256, 0, stream>>>(xl, xr, csr, offs, att, bias, out, n);
}